// Round 1
// 14398.735 us; speedup vs baseline: 1.5386x; 1.5386x over previous
//
#include <hip/hip_runtime.h>

#define HD 1024
#define BB 128
#define TT 128

typedef short short8 __attribute__((ext_vector_type(8)));
typedef float f32x4 __attribute__((ext_vector_type(4)));
typedef unsigned short us4 __attribute__((ext_vector_type(4)));

#define MFMA(a, b, c) __builtin_amdgcn_mfma_f32_16x16x32_bf16((a), (b), (c), 0, 0, 0)

__device__ __forceinline__ float b2f(unsigned short u) {
  union { unsigned int i; float f; } v; v.i = ((unsigned int)u) << 16; return v.f;
}
__device__ __forceinline__ unsigned short f2b(float f) {
  union { float f; unsigned int i; } v; v.f = f;
  unsigned int i = v.i;
  return (unsigned short)((i + 0x7FFFu + ((i >> 16) & 1u)) >> 16);
}
__device__ __forceinline__ short8 ld8(const unsigned short* p) {
  return *reinterpret_cast<const short8*>(p);
}

// Dual-dtype input view: same base pointer, interpreted per runtime flag.
struct DIn { const unsigned short* h; const float* f; };

__device__ __forceinline__ short8 ld8i(const DIn in, size_t idx, int isf) {
  if (isf) {
    const float4* p = (const float4*)(in.f + idx);
    float4 a = p[0], b = p[1];
    short8 r;
    r[0] = (short)f2b(a.x); r[1] = (short)f2b(a.y);
    r[2] = (short)f2b(a.z); r[3] = (short)f2b(a.w);
    r[4] = (short)f2b(b.x); r[5] = (short)f2b(b.y);
    r[6] = (short)f2b(b.z); r[7] = (short)f2b(b.w);
    return r;
  }
  return ld8(in.h + idx);
}
__device__ __forceinline__ float ld1i(const DIn in, size_t idx, int isf) {
  return isf ? in.f[idx] : b2f(in.h[idx]);
}
// Device-coherent 16B load (agent-scope relaxed -> sc1, bypasses L1/per-XCD L2)
__device__ __forceinline__ short8 ld8_coh(const unsigned long long* q) {
  union { unsigned long long u[2]; short8 s; } v;
  v.u[0] = __hip_atomic_load((unsigned long long*)q,     __ATOMIC_RELAXED, __HIP_MEMORY_SCOPE_AGENT);
  v.u[1] = __hip_atomic_load((unsigned long long*)q + 1, __ATOMIC_RELAXED, __HIP_MEMORY_SCOPE_AGENT);
  return v.s;
}
__device__ __forceinline__ float sigm(float x) {
  x = fminf(fmaxf(x, -30.f), 30.f);
  return 1.0f / (1.0f + __expf(-x));
}
__device__ __forceinline__ float tanh_f(float x) {
  x = fminf(fmaxf(x, -15.f), 15.f);
  float e = __expf(2.0f * x);
  return (e - 1.0f) / (e + 1.0f);
}

// ---------------------------------------------------------------------------
// Dtype probe: byte at offset 4i+1 is exp-structured iff data is bf16
// (high byte of bf16 elt 2i). For fp32 it's mid-mantissa (uniform).
// flag: 0 = bf16, 1 = fp32.
// ---------------------------------------------------------------------------
__global__ __launch_bounds__(64) void probe_kernel(const unsigned char* p, int* flag) {
  int t = threadIdx.x;
  unsigned char b = p[t * 4 + 1] & 0x7F;
  int s = (b >= 0x34 && b <= 0x41) ? 1 : 0;
  s += __shfl_xor(s, 1);  s += __shfl_xor(s, 2);  s += __shfl_xor(s, 4);
  s += __shfl_xor(s, 8);  s += __shfl_xor(s, 16); s += __shfl_xor(s, 32);
  if (t == 0) *flag = (s > 32) ? 0 : 1;
}

// ---------------------------------------------------------------------------
// One-time weight conversion -> bf16 (copy if already bf16).
// grid 1536 x 256 threads x 8 elem = 3072*1024 exactly.
// ---------------------------------------------------------------------------
__global__ __launch_bounds__(256) void conv_kernel(DIn in, unsigned short* out,
                                                   const int* flag) {
  const int isf = *flag;
  size_t i = ((size_t)blockIdx.x * 256 + threadIdx.x) * 8;
  *(short8*)(out + i) = ld8i(in, i, isf);
}

// ---------------------------------------------------------------------------
// Persistent GRU scan. Changes vs previous round:
//  - hierarchical barrier: 16 groups x 16 WGs (cacheline-separated group
//    counters + one root counter) instead of 256-way same-line fetch_add
//  - W_hh / W_ih read from pre-converted bf16 buffers (no f2b on the
//    critical path, half the weight bytes)
// ---------------------------------------------------------------------------
struct ScanParams {
  DIn prem, hyp;
  DIn pbih, pbhh, hbih, hbhh;
  const unsigned short *cWihP, *cWhhP, *cWihH, *cWhhH;  // bf16 weights
  unsigned short *hbuf;   // [2][128][1024] bf16 (agent-coherent accesses)
  unsigned short *op;     // [128][128][1024] bf16 (premise outputs, t-major)
  int *bar;               // [0]=root, [8]=flag, [128+g*32]=group counters
};

__global__ __launch_bounds__(128) void scan_kernel(ScanParams P) {
  const int tid = threadIdx.x;
  const int wv = tid >> 6;
  const int lane = tid & 63;
  const int quad = lane >> 4, l16 = lane & 15;
  const int bid = blockIdx.x;
  const int xcd = bid & 7;
  const int y = bid >> 3;
  const int jg = (xcd << 3) | (y & 7);
  const int bc = y >> 3;
  const int row0 = bc << 5;
  const int col0 = jg << 4;
  const int isf = P.bar[8];

  __shared__ float s_gh[32][48];
  __shared__ float s_gx[32][48];
  __shared__ float s_h[32][16];

  const int er = tid >> 2;
  const int ec0 = (tid & 3) << 2;

  for (int q = 0; q < 4; ++q) s_h[er][ec0 + q] = 0.0f;

  float bir[4], biz[4], bin_[4], bhr[4], bhz[4], bhn[4];
  f32x4 gxa[2][3];
  const f32x4 zf = {0.f, 0.f, 0.f, 0.f};

  // prologue: gx(0)
  if (wv == 1) {
    for (int mi = 0; mi < 2; ++mi)
      for (int gi = 0; gi < 3; ++gi) gxa[mi][gi] = zf;
    const size_t x0 = (size_t)(row0 + l16) * TT * HD;
    const size_t x1 = (size_t)(row0 + 16 + l16) * TT * HD;
    for (int kk = 0; kk < 32; ++kk) {
      int k = (kk << 5) + (quad << 3);
      short8 a0 = ld8i(P.prem, x0 + k, isf);
      short8 a1 = ld8i(P.prem, x1 + k, isf);
#pragma unroll
      for (int gi = 0; gi < 3; ++gi) {
        short8 b = ld8(P.cWihP + (size_t)((gi << 10) + col0 + l16) * HD + k);
        gxa[0][gi] = MFMA(a0, b, gxa[0][gi]);
        gxa[1][gi] = MFMA(a1, b, gxa[1][gi]);
      }
    }
  }
  __syncthreads();

  for (int t = 0; t < 256; ++t) {
    if (wv == 0) {
      f32x4 gha[2][3];
#pragma unroll
      for (int mi = 0; mi < 2; ++mi)
#pragma unroll
        for (int gi = 0; gi < 3; ++gi) gha[mi][gi] = zf;
      if (t > 0) {
        const unsigned long long* hq =
            (const unsigned long long*)P.hbuf + (((size_t)(t & 1) * (BB * HD)) >> 2);
        const unsigned short* W = (t < 128) ? P.cWhhP : P.cWhhH;
        const unsigned long long* q0 = hq + (((size_t)(row0 + l16) * HD) >> 2);
        const unsigned long long* q1 = hq + (((size_t)(row0 + 16 + l16) * HD) >> 2);
        for (int kk = 0; kk < 32; ++kk) {
          int k = (kk << 5) + (quad << 3);
          short8 a0 = ld8_coh(q0 + (k >> 2));
          short8 a1 = ld8_coh(q1 + (k >> 2));
#pragma unroll
          for (int gi = 0; gi < 3; ++gi) {
            short8 b = ld8(W + (size_t)((gi << 10) + col0 + l16) * HD + k);
            gha[0][gi] = MFMA(a0, b, gha[0][gi]);
            gha[1][gi] = MFMA(a1, b, gha[1][gi]);
          }
        }
      }
#pragma unroll
      for (int mi = 0; mi < 2; ++mi)
#pragma unroll
        for (int gi = 0; gi < 3; ++gi)
#pragma unroll
          for (int i = 0; i < 4; ++i)
            s_gh[(mi << 4) + (quad << 2) + i][(gi << 4) + l16] = gha[mi][gi][i];
    } else {
#pragma unroll
      for (int mi = 0; mi < 2; ++mi)
#pragma unroll
        for (int gi = 0; gi < 3; ++gi)
#pragma unroll
          for (int i = 0; i < 4; ++i)
            s_gx[(mi << 4) + (quad << 2) + i][(gi << 4) + l16] = gxa[mi][gi][i];
    }
    __syncthreads();

    if (t == 0 || t == 128) {
      const DIn bih = (t < 128) ? P.pbih : P.hbih;
      const DIn bhh = (t < 128) ? P.pbhh : P.hbhh;
#pragma unroll
      for (int q = 0; q < 4; ++q) {
        int g = col0 + ec0 + q;
        bir[q] = ld1i(bih, g, isf);  biz[q] = ld1i(bih, 1024 + g, isf);
        bin_[q] = ld1i(bih, 2048 + g, isf);
        bhr[q] = ld1i(bhh, g, isf);  bhz[q] = ld1i(bhh, 1024 + g, isf);
        bhn[q] = ld1i(bhh, 2048 + g, isf);
      }
    }

    // GRU cell (torch equations), fp32
    unsigned short hout[4];
#pragma unroll
    for (int q = 0; q < 4; ++q) {
      int c = ec0 + q;
      float r = sigm(s_gx[er][c] + bir[q] + s_gh[er][c] + bhr[q]);
      float z = sigm(s_gx[er][16 + c] + biz[q] + s_gh[er][16 + c] + bhz[q]);
      float n = tanh_f(s_gx[er][32 + c] + bin_[q] + r * (s_gh[er][32 + c] + bhn[q]));
      float h = (1.0f - z) * n + z * s_h[er][c];
      s_h[er][c] = h;
      hout[q] = f2b(h);
    }
    {
      union { us4 v; unsigned long long q; } pv;
      pv.v.x = hout[0]; pv.v.y = hout[1]; pv.v.z = hout[2]; pv.v.w = hout[3];
      int grow = row0 + er, gcol = col0 + ec0;
      size_t idx = ((size_t)((t + 1) & 1) * (BB * HD) + (size_t)grow * HD + gcol) >> 2;
      __hip_atomic_store((unsigned long long*)P.hbuf + idx, pv.q,
                         __ATOMIC_RELAXED, __HIP_MEMORY_SCOPE_AGENT);
      if (t < 128)
        *(us4*)(P.op + (size_t)t * (BB * HD) + (size_t)grow * HD + gcol) = pv.v;
    }
    __syncthreads();   // drains vmcnt(0): h-stores visible before arrive

    if (t == 255) break;

    // hierarchical arrival: group counter (16 WGs each), 16th bumps root
    if (tid == 0) {
      int* grp = P.bar + 128 + ((bid >> 4) << 5);
      int old = __hip_atomic_fetch_add(grp, 1, __ATOMIC_RELAXED,
                                       __HIP_MEMORY_SCOPE_AGENT);
      if ((old & 15) == 15)
        __hip_atomic_fetch_add(P.bar, 1, __ATOMIC_RELAXED,
                               __HIP_MEMORY_SCOPE_AGENT);
    }

    // wave1: prefetch gx(t+1) during the barrier wait
    if (wv == 1) {
      int tn = t + 1;
      const DIn X = (tn < 128) ? P.prem : P.hyp;
      const unsigned short* Wi = (tn < 128) ? P.cWihP : P.cWihH;
      int tl = tn & 127;
#pragma unroll
      for (int mi = 0; mi < 2; ++mi)
#pragma unroll
        for (int gi = 0; gi < 3; ++gi) gxa[mi][gi] = zf;
      const size_t x0 = ((size_t)(row0 + l16) * TT + tl) * HD;
      const size_t x1 = ((size_t)(row0 + 16 + l16) * TT + tl) * HD;
      for (int kk = 0; kk < 32; ++kk) {
        int k = (kk << 5) + (quad << 3);
        short8 a0 = ld8i(X, x0 + k, isf);
        short8 a1 = ld8i(X, x1 + k, isf);
#pragma unroll
        for (int gi = 0; gi < 3; ++gi) {
          short8 b = ld8(Wi + (size_t)((gi << 10) + col0 + l16) * HD + k);
          gxa[0][gi] = MFMA(a0, b, gxa[0][gi]);
          gxa[1][gi] = MFMA(a1, b, gxa[1][gi]);
        }
      }
    }

    // release: root reaches 16*(t+1) when all 16 groups arrived
    if (tid == 0) {
      while (__hip_atomic_load(P.bar, __ATOMIC_RELAXED, __HIP_MEMORY_SCOPE_AGENT) <
             ((t + 1) << 4))
        __builtin_amdgcn_s_sleep(4);
    }
    __syncthreads();
  }
}

// ---------------------------------------------------------------------------
// 1024x1024 transpose, dual-dtype input -> bf16 out
// ---------------------------------------------------------------------------
__global__ __launch_bounds__(256) void transpose_kernel(DIn in, unsigned short* out,
                                                        const int* flag) {
  __shared__ unsigned short tile[64][65];
  const int isf = *flag;
  const int b = blockIdx.x;
  const int d0 = (b & 15) << 6, h0 = (b >> 4) << 6;
  const int c = threadIdx.x & 63, rg = threadIdx.x >> 6;
#pragma unroll
  for (int i = 0; i < 16; ++i) {
    int r = (rg << 4) + i;
    size_t idx = (size_t)(h0 + r) * HD + d0 + c;
    tile[r][c] = isf ? f2b(in.f[idx]) : in.h[idx];
  }
  __syncthreads();
#pragma unroll
  for (int i = 0; i < 16; ++i) {
    int r = (rg << 4) + i;
    out[(size_t)(d0 + r) * HD + h0 + c] = tile[c][r];
  }
}

// ---------------------------------------------------------------------------
// Wh = h_last @ W_h -> f32 [128][1024]  (Bt = transposed weight, bf16)
// ---------------------------------------------------------------------------
__global__ __launch_bounds__(256) void wh_kernel(const unsigned short* A,
                                                 const unsigned short* Bt, float* out) {
  const int wvv = threadIdx.x >> 6, lane = threadIdx.x & 63;
  const int quad = lane >> 4, l16 = lane & 15;
  const int m0 = (blockIdx.x >> 3) * 64, n0 = (blockIdx.x & 7) * 128 + wvv * 32;
  const f32x4 zf = {0.f, 0.f, 0.f, 0.f};
  f32x4 acc[4][2];
#pragma unroll
  for (int mi = 0; mi < 4; ++mi) { acc[mi][0] = zf; acc[mi][1] = zf; }
  for (int kk = 0; kk < 32; ++kk) {
    int k = (kk << 5) + (quad << 3);
    short8 a[4], bb[2];
#pragma unroll
    for (int mi = 0; mi < 4; ++mi) a[mi] = ld8(A + (size_t)(m0 + mi * 16 + l16) * HD + k);
#pragma unroll
    for (int nt = 0; nt < 2; ++nt) bb[nt] = ld8(Bt + (size_t)(n0 + nt * 16 + l16) * HD + k);
#pragma unroll
    for (int mi = 0; mi < 4; ++mi)
#pragma unroll
      for (int nt = 0; nt < 2; ++nt) acc[mi][nt] = MFMA(a[mi], bb[nt], acc[mi][nt]);
  }
#pragma unroll
  for (int mi = 0; mi < 4; ++mi)
#pragma unroll
    for (int nt = 0; nt < 2; ++nt)
#pragma unroll
      for (int i = 0; i < 4; ++i)
        out[(size_t)(m0 + mi * 16 + quad * 4 + i) * HD + n0 + nt * 16 + l16] = acc[mi][nt][i];
}

// ---------------------------------------------------------------------------
// scores[r=(t,b)] = sum_d tanh(Y@W_y[r,d] + Wh[b,d]) * Walpha[d]
// ---------------------------------------------------------------------------
__global__ __launch_bounds__(256) void score_kernel(const unsigned short* op,
                                                    const unsigned short* WyT,
                                                    const float* Wh,
                                                    DIn Walpha,
                                                    float* scores,
                                                    const int* flag) {
  const int isf = *flag;
  const int wvv = threadIdx.x >> 6, lane = threadIdx.x & 63;
  const int quad = lane >> 4, l16 = lane & 15;
  const int r0 = blockIdx.x * 64;
  __shared__ float ssc[4][64];
  float sp[4][4];
#pragma unroll
  for (int mi = 0; mi < 4; ++mi)
#pragma unroll
    for (int i = 0; i < 4; ++i) sp[mi][i] = 0.f;
  const f32x4 zf = {0.f, 0.f, 0.f, 0.f};

  for (int dc = 0; dc < 8; ++dc) {
    const int n0 = dc * 128 + wvv * 32;
    f32x4 acc[4][2];
#pragma unroll
    for (int mi = 0; mi < 4; ++mi) { acc[mi][0] = zf; acc[mi][1] = zf; }
    for (int kk = 0; kk < 32; ++kk) {
      int k = (kk << 5) + (quad << 3);
      short8 a[4], bb[2];
#pragma unroll
      for (int mi = 0; mi < 4; ++mi) a[mi] = ld8(op + (size_t)(r0 + mi * 16 + l16) * HD + k);
#pragma unroll
      for (int nt = 0; nt < 2; ++nt) bb[nt] = ld8(WyT + (size_t)(n0 + nt * 16 + l16) * HD + k);
#pragma unroll
      for (int mi = 0; mi < 4; ++mi)
#pragma unroll
        for (int nt = 0; nt < 2; ++nt) acc[mi][nt] = MFMA(a[mi], bb[nt], acc[mi][nt]);
    }
    float wa[2];
#pragma unroll
    for (int nt = 0; nt < 2; ++nt) wa[nt] = ld1i(Walpha, n0 + nt * 16 + l16, isf);
#pragma unroll
    for (int mi = 0; mi < 4; ++mi)
#pragma unroll
      for (int nt = 0; nt < 2; ++nt)
#pragma unroll
        for (int i = 0; i < 4; ++i) {
          int r = r0 + mi * 16 + quad * 4 + i;
          int bb2 = r & 127;
          int d = n0 + nt * 16 + l16;
          float v = tanh_f(acc[mi][nt][i] + Wh[(size_t)bb2 * HD + d]);
          sp[mi][i] += v * wa[nt];
        }
  }
#pragma unroll
  for (int mi = 0; mi < 4; ++mi)
#pragma unroll
    for (int i = 0; i < 4; ++i) {
      float v = sp[mi][i];
      v += __shfl_xor(v, 1); v += __shfl_xor(v, 2);
      v += __shfl_xor(v, 4); v += __shfl_xor(v, 8);
      sp[mi][i] = v;
    }
  if (l16 == 0) {
#pragma unroll
    for (int mi = 0; mi < 4; ++mi)
#pragma unroll
      for (int i = 0; i < 4; ++i) ssc[wvv][mi * 16 + quad * 4 + i] = sp[mi][i];
  }
  __syncthreads();
  if (threadIdx.x < 64)
    scores[r0 + threadIdx.x] =
        ssc[0][threadIdx.x] + ssc[1][threadIdx.x] + ssc[2][threadIdx.x] + ssc[3][threadIdx.x];
}

// ---------------------------------------------------------------------------
// per-b softmax over t + r[b,h] = sum_t alpha[t] * Y[b,t,h]
// ---------------------------------------------------------------------------
__global__ __launch_bounds__(256) void softrv_kernel(const float* scores,
                                                     const unsigned short* op,
                                                     unsigned short* rbf) {
  const int b = blockIdx.x;
  const int tid = threadIdx.x, wvv = tid >> 6, lane = tid & 63;
  __shared__ float sal[128];
  __shared__ float red[8];
  float sv = -3.0e38f;
  if (tid < 128) sv = scores[tid * BB + b];
  float m = sv;
  m = fmaxf(m, __shfl_xor(m, 1));  m = fmaxf(m, __shfl_xor(m, 2));
  m = fmaxf(m, __shfl_xor(m, 4));  m = fmaxf(m, __shfl_xor(m, 8));
  m = fmaxf(m, __shfl_xor(m, 16)); m = fmaxf(m, __shfl_xor(m, 32));
  if (lane == 0) red[wvv] = m;
  __syncthreads();
  float M = fmaxf(fmaxf(red[0], red[1]), fmaxf(red[2], red[3]));
  float e = (tid < 128) ? __expf(sv - M) : 0.0f;
  float s = e;
  s += __shfl_xor(s, 1);  s += __shfl_xor(s, 2);  s += __shfl_xor(s, 4);
  s += __shfl_xor(s, 8);  s += __shfl_xor(s, 16); s += __shfl_xor(s, 32);
  if (lane == 0) red[4 + wvv] = s;
  __syncthreads();
  float S = red[4] + red[5] + red[6] + red[7];
  if (tid < 128) sal[tid] = e / S;
  __syncthreads();
  float a0 = 0, a1 = 0, a2 = 0, a3 = 0;
  const unsigned short* base = op + (size_t)b * HD + tid * 4;
  for (int t2 = 0; t2 < 128; ++t2) {
    float w = sal[t2];
    us4 v = *(const us4*)(base + (size_t)t2 * (BB * HD));
    a0 += w * b2f(v.x); a1 += w * b2f(v.y); a2 += w * b2f(v.z); a3 += w * b2f(v.w);
  }
  us4 o; o.x = f2b(a0); o.y = f2b(a1); o.z = f2b(a2); o.w = f2b(a3);
  *(us4*)(rbf + (size_t)b * HD + tid * 4) = o;
}

// ---------------------------------------------------------------------------
// h_star = tanh(r @ W_p + h_last @ W_x)
// ---------------------------------------------------------------------------
__global__ __launch_bounds__(256) void hstar_kernel(const unsigned short* rbf,
                                                    const unsigned short* hlast,
                                                    const unsigned short* WpT,
                                                    const unsigned short* WxT,
                                                    unsigned short* hstar) {
  const int wvv = threadIdx.x >> 6, lane = threadIdx.x & 63;
  const int quad = lane >> 4, l16 = lane & 15;
  const int m0 = (blockIdx.x >> 3) * 64, n0 = (blockIdx.x & 7) * 128 + wvv * 32;
  const f32x4 zf = {0.f, 0.f, 0.f, 0.f};
  f32x4 acc[4][2];
#pragma unroll
  for (int mi = 0; mi < 4; ++mi) { acc[mi][0] = zf; acc[mi][1] = zf; }
  for (int kk = 0; kk < 64; ++kk) {
    int k = (kk << 5) + (quad << 3);
    const unsigned short* Ap; const unsigned short* Bp; int kl;
    if (kk < 32) { Ap = rbf;   Bp = WpT; kl = k; }
    else         { Ap = hlast; Bp = WxT; kl = k - 1024; }
    short8 a[4], bb[2];
#pragma unroll
    for (int mi = 0; mi < 4; ++mi) a[mi] = ld8(Ap + (size_t)(m0 + mi * 16 + l16) * HD + kl);
#pragma unroll
    for (int nt = 0; nt < 2; ++nt) bb[nt] = ld8(Bp + (size_t)(n0 + nt * 16 + l16) * HD + kl);
#pragma unroll
    for (int mi = 0; mi < 4; ++mi)
#pragma unroll
      for (int nt = 0; nt < 2; ++nt) acc[mi][nt] = MFMA(a[mi], bb[nt], acc[mi][nt]);
  }
#pragma unroll
  for (int mi = 0; mi < 4; ++mi)
#pragma unroll
    for (int nt = 0; nt < 2; ++nt)
#pragma unroll
      for (int i = 0; i < 4; ++i)
        hstar[(size_t)(m0 + mi * 16 + quad * 4 + i) * HD + n0 + nt * 16 + l16] =
            f2b(tanh_f(acc[mi][nt][i]));
}

// ---------------------------------------------------------------------------
// logits = tanh(h_star @ out_w^T + out_b); out = log_softmax (dtype-matched)
// ---------------------------------------------------------------------------
__global__ __launch_bounds__(64) void out_kernel(const unsigned short* hstar,
                                                 DIn outw, DIn outb,
                                                 void* dout, const int* flag) {
  const int isf = *flag;
  const int b = blockIdx.x, lane = threadIdx.x;
  float l0 = 0, l1 = 0, l2 = 0;
  const short8* ph = (const short8*)(hstar + (size_t)b * HD + lane * 16);
  short8 h0 = ph[0], h1 = ph[1];
  for (int c = 0; c < 3; ++c) {
    short8 w0 = ld8i(outw, (size_t)c * HD + lane * 16, isf);
    short8 w1 = ld8i(outw, (size_t)c * HD + lane * 16 + 8, isf);
    float s = 0;
#pragma unroll
    for (int j = 0; j < 8; ++j)
      s += b2f((unsigned short)h0[j]) * b2f((unsigned short)w0[j]) +
           b2f((unsigned short)h1[j]) * b2f((unsigned short)w1[j]);
    s += __shfl_xor(s, 1);  s += __shfl_xor(s, 2);  s += __shfl_xor(s, 4);
    s += __shfl_xor(s, 8);  s += __shfl_xor(s, 16); s += __shfl_xor(s, 32);
    float v = tanh_f(s + ld1i(outb, c, isf));
    if (c == 0) l0 = v; else if (c == 1) l1 = v; else l2 = v;
  }
  float mx = fmaxf(l0, fmaxf(l1, l2));
  float lse = mx + logf(__expf(l0 - mx) + __expf(l1 - mx) + __expf(l2 - mx));
  if (lane < 3) {
    float v = ((lane == 0) ? l0 : (lane == 1) ? l1 : l2) - lse;
    if (isf) ((float*)dout)[b * 3 + lane] = v;
    else     ((unsigned short*)dout)[b * 3 + lane] = f2b(v);
  }
}

// ---------------------------------------------------------------------------
extern "C" void kernel_launch(void* const* d_in, const int* in_sizes, int n_in,
                              void* d_out, int out_size, void* d_ws, size_t ws_size,
                              hipStream_t stream) {
  DIn prem{(const unsigned short*)d_in[0],  (const float*)d_in[0]};
  DIn hyp {(const unsigned short*)d_in[1],  (const float*)d_in[1]};
  DIn pWih{(const unsigned short*)d_in[2],  (const float*)d_in[2]};
  DIn pWhh{(const unsigned short*)d_in[3],  (const float*)d_in[3]};
  DIn pbih{(const unsigned short*)d_in[4],  (const float*)d_in[4]};
  DIn pbhh{(const unsigned short*)d_in[5],  (const float*)d_in[5]};
  DIn hWih{(const unsigned short*)d_in[6],  (const float*)d_in[6]};
  DIn hWhh{(const unsigned short*)d_in[7],  (const float*)d_in[7]};
  DIn hbih{(const unsigned short*)d_in[8],  (const float*)d_in[8]};
  DIn hbhh{(const unsigned short*)d_in[9],  (const float*)d_in[9]};
  DIn Wy  {(const unsigned short*)d_in[10], (const float*)d_in[10]};
  DIn Whm {(const unsigned short*)d_in[11], (const float*)d_in[11]};
  DIn Wal {(const unsigned short*)d_in[12], (const float*)d_in[12]};
  DIn Wx  {(const unsigned short*)d_in[13], (const float*)d_in[13]};
  DIn Wp  {(const unsigned short*)d_in[14], (const float*)d_in[14]};
  DIn outw{(const unsigned short*)d_in[15], (const float*)d_in[15]};
  DIn outb{(const unsigned short*)d_in[16], (const float*)d_in[16]};

  // Workspace: 62 MB total (transposes overlaid in tb0/tb1)
  char* ws = (char*)d_ws;
  int*            bar   = (int*)ws;                          // [0]=root,[8]=flag,[128+]=grp
  unsigned short* hbuf  = (unsigned short*)(ws + 4096);      // 512 KB
  float*          WhRes = (float*)(ws + 528384);             // 512 KB
  float*          scr   = (float*)(ws + 1052672);            // 64 KB
  unsigned short* rbf   = (unsigned short*)(ws + 1118208);   // 256 KB
  unsigned short* hstar = (unsigned short*)(ws + 1380352);   // 256 KB
  unsigned short* tb0   = (unsigned short*)(ws + 2097152);   // 2 MB
  unsigned short* tb1   = (unsigned short*)(ws + 4194304);   // 2 MB
  unsigned short* op    = (unsigned short*)(ws + 6291456);   // 32 MB -> ends 38 MB
  unsigned short* cWihP = (unsigned short*)(ws + 39845888);  // 6 MB bf16 weights
  unsigned short* cWhhP = (unsigned short*)(ws + 46137344);  // 6 MB
  unsigned short* cWihH = (unsigned short*)(ws + 52428800);  // 6 MB
  unsigned short* cWhhH = (unsigned short*)(ws + 58720256);  // 6 MB -> ends 62 MB

  hipMemsetAsync(d_ws, 0, 4096, stream);
  hipLaunchKernelGGL(probe_kernel, dim3(1), dim3(64), 0, stream,
                     (const unsigned char*)d_in[0], bar + 8);

  // one-time bf16 weight conversion (3072*1024 each; grid 1536*256*8 exact)
  hipLaunchKernelGGL(conv_kernel, dim3(1536), dim3(256), 0, stream, pWih, cWihP, bar + 8);
  hipLaunchKernelGGL(conv_kernel, dim3(1536), dim3(256), 0, stream, pWhh, cWhhP, bar + 8);
  hipLaunchKernelGGL(conv_kernel, dim3(1536), dim3(256), 0, stream, hWih, cWihH, bar + 8);
  hipLaunchKernelGGL(conv_kernel, dim3(1536), dim3(256), 0, stream, hWhh, cWhhH, bar + 8);

  ScanParams sp{prem, hyp, pbih, pbhh, hbih, hbhh,
                cWihP, cWhhP, cWihH, cWhhH, hbuf, op, bar};
  hipLaunchKernelGGL(scan_kernel, dim3(256), dim3(128), 0, stream, sp);

  hipLaunchKernelGGL(transpose_kernel, dim3(256), dim3(256), 0, stream, Whm, tb0, bar + 8);
  hipLaunchKernelGGL(wh_kernel, dim3(16), dim3(256), 0, stream, hbuf, tb0, WhRes);

  hipLaunchKernelGGL(transpose_kernel, dim3(256), dim3(256), 0, stream, Wy, tb0, bar + 8);
  hipLaunchKernelGGL(score_kernel, dim3(256), dim3(256), 0, stream, op, tb0, WhRes,
                     Wal, scr, bar + 8);
  hipLaunchKernelGGL(softrv_kernel, dim3(128), dim3(256), 0, stream, scr, op, rbf);

  hipLaunchKernelGGL(transpose_kernel, dim3(256), dim3(256), 0, stream, Wp, tb0, bar + 8);
  hipLaunchKernelGGL(transpose_kernel, dim3(256), dim3(256), 0, stream, Wx, tb1, bar + 8);
  hipLaunchKernelGGL(hstar_kernel, dim3(16), dim3(256), 0, stream, rbf, hbuf, tb0, tb1, hstar);

  hipLaunchKernelGGL(out_kernel, dim3(128), dim3(64), 0, stream, hstar, outw, outb,
                     d_out, bar + 8);
}

// Round 2
// 8598.669 us; speedup vs baseline: 2.5764x; 1.6745x over previous
//
#include <hip/hip_runtime.h>

#define HD 1024
#define BB 128
#define TT 128

typedef short short8 __attribute__((ext_vector_type(8)));
typedef float f32x4 __attribute__((ext_vector_type(4)));
typedef unsigned short us4 __attribute__((ext_vector_type(4)));

#define MFMA(a, b, c) __builtin_amdgcn_mfma_f32_16x16x32_bf16((a), (b), (c), 0, 0, 0)

__device__ __forceinline__ float b2f(unsigned short u) {
  union { unsigned int i; float f; } v; v.i = ((unsigned int)u) << 16; return v.f;
}
__device__ __forceinline__ unsigned short f2b(float f) {
  union { float f; unsigned int i; } v; v.f = f;
  unsigned int i = v.i;
  return (unsigned short)((i + 0x7FFFu + ((i >> 16) & 1u)) >> 16);
}
__device__ __forceinline__ short8 ld8(const unsigned short* p) {
  return *reinterpret_cast<const short8*>(p);
}

// Dual-dtype input view: same base pointer, interpreted per runtime flag.
struct DIn { const unsigned short* h; const float* f; };

__device__ __forceinline__ short8 ld8i(const DIn in, size_t idx, int isf) {
  if (isf) {
    const float4* p = (const float4*)(in.f + idx);
    float4 a = p[0], b = p[1];
    short8 r;
    r[0] = (short)f2b(a.x); r[1] = (short)f2b(a.y);
    r[2] = (short)f2b(a.z); r[3] = (short)f2b(a.w);
    r[4] = (short)f2b(b.x); r[5] = (short)f2b(b.y);
    r[6] = (short)f2b(b.z); r[7] = (short)f2b(b.w);
    return r;
  }
  return ld8(in.h + idx);
}
__device__ __forceinline__ float ld1i(const DIn in, size_t idx, int isf) {
  return isf ? in.f[idx] : b2f(in.h[idx]);
}
// Device-coherent 16B load (agent-scope relaxed -> sc1, bypasses L1/per-XCD L2)
__device__ __forceinline__ short8 ld8_coh(const unsigned long long* q) {
  union { unsigned long long u[2]; short8 s; } v;
  v.u[0] = __hip_atomic_load((unsigned long long*)q,     __ATOMIC_RELAXED, __HIP_MEMORY_SCOPE_AGENT);
  v.u[1] = __hip_atomic_load((unsigned long long*)q + 1, __ATOMIC_RELAXED, __HIP_MEMORY_SCOPE_AGENT);
  return v.s;
}
__device__ __forceinline__ float sigm(float x) {
  x = fminf(fmaxf(x, -30.f), 30.f);
  return 1.0f / (1.0f + __expf(-x));
}
__device__ __forceinline__ float tanh_f(float x) {
  x = fminf(fmaxf(x, -15.f), 15.f);
  float e = __expf(2.0f * x);
  return (e - 1.0f) / (e + 1.0f);
}

// ---------------------------------------------------------------------------
// Dtype probe: byte at offset 4i+1 is exp-structured iff data is bf16.
// flag: 0 = bf16, 1 = fp32.  (flag lives at bar[992])
// ---------------------------------------------------------------------------
__global__ __launch_bounds__(64) void probe_kernel(const unsigned char* p, int* flag) {
  int t = threadIdx.x;
  unsigned char b = p[t * 4 + 1] & 0x7F;
  int s = (b >= 0x34 && b <= 0x41) ? 1 : 0;
  s += __shfl_xor(s, 1);  s += __shfl_xor(s, 2);  s += __shfl_xor(s, 4);
  s += __shfl_xor(s, 8);  s += __shfl_xor(s, 16); s += __shfl_xor(s, 32);
  if (t == 0) *flag = (s > 32) ? 0 : 1;
}

// ---------------------------------------------------------------------------
// One-time weight conversion -> bf16 (copy if already bf16).
// ---------------------------------------------------------------------------
__global__ __launch_bounds__(256) void conv_kernel(DIn in, unsigned short* out,
                                                   const int* flag) {
  const int isf = *flag;
  size_t i = ((size_t)blockIdx.x * 256 + threadIdx.x) * 8;
  *(short8*)(out + i) = ld8i(in, i, isf);
}

// ---------------------------------------------------------------------------
// Persistent GRU scan. Changes vs previous round:
//  - flag-based hierarchical barrier (no RMW): member flag stores -> leader
//    ballot-poll -> leader flag -> leaders ballot-poll shared line -> group
//    release word on a separate cacheline, <=16 pollers per line
//  - 4 waves/WG: waves 0/1 split gh over K (16 serial MALL loads each,
//    unroll-2 pipelined), waves 2/3 split gx prefetch over K; partials
//    summed in the GRU cell
// Barrier layout in bar[]: [0..15] leader flags (own line); group g:
//   bar[64+32g .. +15] member flags, bar[64+32g+24] release word (2nd line);
//   bar[992] dtype flag.
// ---------------------------------------------------------------------------
struct ScanParams {
  DIn prem, hyp;
  DIn pbih, pbhh, hbih, hbhh;
  const unsigned short *cWihP, *cWhhP, *cWihH, *cWhhH;  // bf16 weights
  unsigned short *hbuf;   // [2][128][1024] bf16 (agent-coherent accesses)
  unsigned short *op;     // [128][128][1024] bf16 (premise outputs, t-major)
  int *bar;
};

__global__ __launch_bounds__(256) void scan_kernel(ScanParams P) {
  const int tid = threadIdx.x;
  const int wv = tid >> 6;
  const int lane = tid & 63;
  const int quad = lane >> 4, l16 = lane & 15;
  const int bid = blockIdx.x;
  const int xcd = bid & 7;
  const int y = bid >> 3;
  const int jg = (xcd << 3) | (y & 7);
  const int bc = y >> 3;
  const int row0 = bc << 5;
  const int col0 = jg << 4;
  const int gid = bid >> 4, mem = bid & 15;
  const int isf = P.bar[992];

  __shared__ float s_gh[2][32][52];
  __shared__ float s_gx[2][32][52];
  __shared__ float s_h[32][16];

  const int er = tid >> 2;            // valid for tid < 128
  const int ec0 = (tid & 3) << 2;

  if (tid < 128)
    for (int q = 0; q < 4; ++q) s_h[er][ec0 + q] = 0.0f;

  float bir[4], biz[4], bin_[4], bhr[4], bhz[4], bhn[4];
  f32x4 gxa[2][3];
  const f32x4 zf = {0.f, 0.f, 0.f, 0.f};

  int* grpl = P.bar + 64 + (gid << 5);

  // prologue: gx(0) on waves 2/3 (K-split)
  if (wv >= 2) {
#pragma unroll
    for (int mi = 0; mi < 2; ++mi)
#pragma unroll
      for (int gi = 0; gi < 3; ++gi) gxa[mi][gi] = zf;
    const int kk0 = (wv - 2) << 4;
    const size_t x0 = (size_t)(row0 + l16) * TT * HD;
    const size_t x1 = (size_t)(row0 + 16 + l16) * TT * HD;
#pragma unroll 2
    for (int kk = kk0; kk < kk0 + 16; ++kk) {
      int k = (kk << 5) + (quad << 3);
      short8 a0 = ld8i(P.prem, x0 + k, isf);
      short8 a1 = ld8i(P.prem, x1 + k, isf);
#pragma unroll
      for (int gi = 0; gi < 3; ++gi) {
        short8 b = ld8(P.cWihP + (size_t)((gi << 10) + col0 + l16) * HD + k);
        gxa[0][gi] = MFMA(a0, b, gxa[0][gi]);
        gxa[1][gi] = MFMA(a1, b, gxa[1][gi]);
      }
    }
  }
  __syncthreads();

  for (int t = 0; t < 256; ++t) {
    if (wv < 2) {
      // gh(t), K-split across waves 0/1
      f32x4 gha[2][3];
#pragma unroll
      for (int mi = 0; mi < 2; ++mi)
#pragma unroll
        for (int gi = 0; gi < 3; ++gi) gha[mi][gi] = zf;
      if (t > 0) {
        const unsigned long long* hq =
            (const unsigned long long*)P.hbuf + (((size_t)(t & 1) * (BB * HD)) >> 2);
        const unsigned short* W = (t < 128) ? P.cWhhP : P.cWhhH;
        const unsigned long long* q0 = hq + (((size_t)(row0 + l16) * HD) >> 2);
        const unsigned long long* q1 = hq + (((size_t)(row0 + 16 + l16) * HD) >> 2);
        const int kk0 = wv << 4;
#pragma unroll 2
        for (int kk = kk0; kk < kk0 + 16; ++kk) {
          int k = (kk << 5) + (quad << 3);
          short8 a0 = ld8_coh(q0 + (k >> 2));
          short8 a1 = ld8_coh(q1 + (k >> 2));
#pragma unroll
          for (int gi = 0; gi < 3; ++gi) {
            short8 b = ld8(W + (size_t)((gi << 10) + col0 + l16) * HD + k);
            gha[0][gi] = MFMA(a0, b, gha[0][gi]);
            gha[1][gi] = MFMA(a1, b, gha[1][gi]);
          }
        }
      }
#pragma unroll
      for (int mi = 0; mi < 2; ++mi)
#pragma unroll
        for (int gi = 0; gi < 3; ++gi)
#pragma unroll
          for (int i = 0; i < 4; ++i)
            s_gh[wv][(mi << 4) + (quad << 2) + i][(gi << 4) + l16] = gha[mi][gi][i];
    } else {
      const int w2 = wv - 2;
#pragma unroll
      for (int mi = 0; mi < 2; ++mi)
#pragma unroll
        for (int gi = 0; gi < 3; ++gi)
#pragma unroll
          for (int i = 0; i < 4; ++i)
            s_gx[w2][(mi << 4) + (quad << 2) + i][(gi << 4) + l16] = gxa[mi][gi][i];
    }
    __syncthreads();

    if ((t == 0 || t == 128) && tid < 128) {
      const DIn bih = (t < 128) ? P.pbih : P.hbih;
      const DIn bhh = (t < 128) ? P.pbhh : P.hbhh;
#pragma unroll
      for (int q = 0; q < 4; ++q) {
        int g = col0 + ec0 + q;
        bir[q] = ld1i(bih, g, isf);  biz[q] = ld1i(bih, 1024 + g, isf);
        bin_[q] = ld1i(bih, 2048 + g, isf);
        bhr[q] = ld1i(bhh, g, isf);  bhz[q] = ld1i(bhh, 1024 + g, isf);
        bhn[q] = ld1i(bhh, 2048 + g, isf);
      }
    }

    // GRU cell (torch equations), fp32 — threads 0..127
    if (tid < 128) {
      unsigned short hout[4];
#pragma unroll
      for (int q = 0; q < 4; ++q) {
        int c = ec0 + q;
        float gxr = s_gx[0][er][c]      + s_gx[1][er][c];
        float gxz = s_gx[0][er][16 + c] + s_gx[1][er][16 + c];
        float gxn = s_gx[0][er][32 + c] + s_gx[1][er][32 + c];
        float ghr = s_gh[0][er][c]      + s_gh[1][er][c];
        float ghz = s_gh[0][er][16 + c] + s_gh[1][er][16 + c];
        float ghn = s_gh[0][er][32 + c] + s_gh[1][er][32 + c];
        float r = sigm(gxr + bir[q] + ghr + bhr[q]);
        float z = sigm(gxz + biz[q] + ghz + bhz[q]);
        float n = tanh_f(gxn + bin_[q] + r * (ghn + bhn[q]));
        float h = (1.0f - z) * n + z * s_h[er][c];
        s_h[er][c] = h;
        hout[q] = f2b(h);
      }
      union { us4 v; unsigned long long q; } pv;
      pv.v.x = hout[0]; pv.v.y = hout[1]; pv.v.z = hout[2]; pv.v.w = hout[3];
      int grow = row0 + er, gcol = col0 + ec0;
      size_t idx = ((size_t)((t + 1) & 1) * (BB * HD) + (size_t)grow * HD + gcol) >> 2;
      __hip_atomic_store((unsigned long long*)P.hbuf + idx, pv.q,
                         __ATOMIC_RELAXED, __HIP_MEMORY_SCOPE_AGENT);
      if (t < 128)
        *(us4*)(P.op + (size_t)t * (BB * HD) + (size_t)grow * HD + gcol) = pv.v;
    }
    __syncthreads();   // drains vmcnt(0): h-stores visible before arrival flag

    if (t == 255) break;

    // arrival: each WG stores its own flag dword (no RMW contention)
    if (tid == 0)
      __hip_atomic_store(grpl + mem, t + 1, __ATOMIC_RELAXED,
                         __HIP_MEMORY_SCOPE_AGENT);

    // waves 2/3: prefetch gx(t+1) during the barrier window
    if (wv >= 2) {
      int tn = t + 1;
      const DIn X = (tn < 128) ? P.prem : P.hyp;
      const unsigned short* Wi = (tn < 128) ? P.cWihP : P.cWihH;
      int tl = tn & 127;
#pragma unroll
      for (int mi = 0; mi < 2; ++mi)
#pragma unroll
        for (int gi = 0; gi < 3; ++gi) gxa[mi][gi] = zf;
      const int kk0 = (wv - 2) << 4;
      const size_t x0 = ((size_t)(row0 + l16) * TT + tl) * HD;
      const size_t x1 = ((size_t)(row0 + 16 + l16) * TT + tl) * HD;
#pragma unroll 2
      for (int kk = kk0; kk < kk0 + 16; ++kk) {
        int k = (kk << 5) + (quad << 3);
        short8 a0 = ld8i(X, x0 + k, isf);
        short8 a1 = ld8i(X, x1 + k, isf);
#pragma unroll
        for (int gi = 0; gi < 3; ++gi) {
          short8 b = ld8(Wi + (size_t)((gi << 10) + col0 + l16) * HD + k);
          gxa[0][gi] = MFMA(a0, b, gxa[0][gi]);
          gxa[1][gi] = MFMA(a1, b, gxa[1][gi]);
        }
      }
    }

    // release: 3 store->poll hops, <=16 pollers per line
    if (wv == 0) {
      if (mem == 0) {
        // leader: ballot-poll the 16 member flags (one coalesced load)
        for (;;) {
          int v = (lane < 16)
                      ? __hip_atomic_load(grpl + lane, __ATOMIC_RELAXED,
                                          __HIP_MEMORY_SCOPE_AGENT)
                      : t + 1;
          if (__ballot(v >= t + 1) == ~0ull) break;
          __builtin_amdgcn_s_sleep(2);
        }
        if (lane == 0)
          __hip_atomic_store(P.bar + gid, t + 1, __ATOMIC_RELAXED,
                             __HIP_MEMORY_SCOPE_AGENT);
        // all leaders poll the shared leader line
        for (;;) {
          int v = (lane < 16)
                      ? __hip_atomic_load(P.bar + lane, __ATOMIC_RELAXED,
                                          __HIP_MEMORY_SCOPE_AGENT)
                      : t + 1;
          if (__ballot(v >= t + 1) == ~0ull) break;
          __builtin_amdgcn_s_sleep(2);
        }
        if (lane == 0)
          __hip_atomic_store(grpl + 24, t + 1, __ATOMIC_RELAXED,
                             __HIP_MEMORY_SCOPE_AGENT);
      } else if (lane == 0) {
        while (__hip_atomic_load(grpl + 24, __ATOMIC_RELAXED,
                                 __HIP_MEMORY_SCOPE_AGENT) < t + 1)
          __builtin_amdgcn_s_sleep(2);
      }
    }
    __syncthreads();
  }
}

// ---------------------------------------------------------------------------
// 1024x1024 transpose, dual-dtype input -> bf16 out
// ---------------------------------------------------------------------------
__global__ __launch_bounds__(256) void transpose_kernel(DIn in, unsigned short* out,
                                                        const int* flag) {
  __shared__ unsigned short tile[64][65];
  const int isf = *flag;
  const int b = blockIdx.x;
  const int d0 = (b & 15) << 6, h0 = (b >> 4) << 6;
  const int c = threadIdx.x & 63, rg = threadIdx.x >> 6;
#pragma unroll
  for (int i = 0; i < 16; ++i) {
    int r = (rg << 4) + i;
    size_t idx = (size_t)(h0 + r) * HD + d0 + c;
    tile[r][c] = isf ? f2b(in.f[idx]) : in.h[idx];
  }
  __syncthreads();
#pragma unroll
  for (int i = 0; i < 16; ++i) {
    int r = (rg << 4) + i;
    out[(size_t)(d0 + r) * HD + h0 + c] = tile[c][r];
  }
}

// ---------------------------------------------------------------------------
// Wh = h_last @ W_h -> f32 [128][1024]  (Bt = transposed weight, bf16)
// ---------------------------------------------------------------------------
__global__ __launch_bounds__(256) void wh_kernel(const unsigned short* A,
                                                 const unsigned short* Bt, float* out) {
  const int wvv = threadIdx.x >> 6, lane = threadIdx.x & 63;
  const int quad = lane >> 4, l16 = lane & 15;
  const int m0 = (blockIdx.x >> 3) * 64, n0 = (blockIdx.x & 7) * 128 + wvv * 32;
  const f32x4 zf = {0.f, 0.f, 0.f, 0.f};
  f32x4 acc[4][2];
#pragma unroll
  for (int mi = 0; mi < 4; ++mi) { acc[mi][0] = zf; acc[mi][1] = zf; }
  for (int kk = 0; kk < 32; ++kk) {
    int k = (kk << 5) + (quad << 3);
    short8 a[4], bb[2];
#pragma unroll
    for (int mi = 0; mi < 4; ++mi) a[mi] = ld8(A + (size_t)(m0 + mi * 16 + l16) * HD + k);
#pragma unroll
    for (int nt = 0; nt < 2; ++nt) bb[nt] = ld8(Bt + (size_t)(n0 + nt * 16 + l16) * HD + k);
#pragma unroll
    for (int mi = 0; mi < 4; ++mi)
#pragma unroll
      for (int nt = 0; nt < 2; ++nt) acc[mi][nt] = MFMA(a[mi], bb[nt], acc[mi][nt]);
  }
#pragma unroll
  for (int mi = 0; mi < 4; ++mi)
#pragma unroll
    for (int nt = 0; nt < 2; ++nt)
#pragma unroll
      for (int i = 0; i < 4; ++i)
        out[(size_t)(m0 + mi * 16 + quad * 4 + i) * HD + n0 + nt * 16 + l16] = acc[mi][nt][i];
}

// ---------------------------------------------------------------------------
// scores[r=(t,b)] = sum_d tanh(Y@W_y[r,d] + Wh[b,d]) * Walpha[d]
// ---------------------------------------------------------------------------
__global__ __launch_bounds__(256) void score_kernel(const unsigned short* op,
                                                    const unsigned short* WyT,
                                                    const float* Wh,
                                                    DIn Walpha,
                                                    float* scores,
                                                    const int* flag) {
  const int isf = *flag;
  const int wvv = threadIdx.x >> 6, lane = threadIdx.x & 63;
  const int quad = lane >> 4, l16 = lane & 15;
  const int r0 = blockIdx.x * 64;
  __shared__ float ssc[4][64];
  float sp[4][4];
#pragma unroll
  for (int mi = 0; mi < 4; ++mi)
#pragma unroll
    for (int i = 0; i < 4; ++i) sp[mi][i] = 0.f;
  const f32x4 zf = {0.f, 0.f, 0.f, 0.f};

  for (int dc = 0; dc < 8; ++dc) {
    const int n0 = dc * 128 + wvv * 32;
    f32x4 acc[4][2];
#pragma unroll
    for (int mi = 0; mi < 4; ++mi) { acc[mi][0] = zf; acc[mi][1] = zf; }
    for (int kk = 0; kk < 32; ++kk) {
      int k = (kk << 5) + (quad << 3);
      short8 a[4], bb[2];
#pragma unroll
      for (int mi = 0; mi < 4; ++mi) a[mi] = ld8(op + (size_t)(r0 + mi * 16 + l16) * HD + k);
#pragma unroll
      for (int nt = 0; nt < 2; ++nt) bb[nt] = ld8(WyT + (size_t)(n0 + nt * 16 + l16) * HD + k);
#pragma unroll
      for (int mi = 0; mi < 4; ++mi)
#pragma unroll
        for (int nt = 0; nt < 2; ++nt) acc[mi][nt] = MFMA(a[mi], bb[nt], acc[mi][nt]);
    }
    float wa[2];
#pragma unroll
    for (int nt = 0; nt < 2; ++nt) wa[nt] = ld1i(Walpha, n0 + nt * 16 + l16, isf);
#pragma unroll
    for (int mi = 0; mi < 4; ++mi)
#pragma unroll
      for (int nt = 0; nt < 2; ++nt)
#pragma unroll
        for (int i = 0; i < 4; ++i) {
          int r = r0 + mi * 16 + quad * 4 + i;
          int bb2 = r & 127;
          int d = n0 + nt * 16 + l16;
          float v = tanh_f(acc[mi][nt][i] + Wh[(size_t)bb2 * HD + d]);
          sp[mi][i] += v * wa[nt];
        }
  }
#pragma unroll
  for (int mi = 0; mi < 4; ++mi)
#pragma unroll
    for (int i = 0; i < 4; ++i) {
      float v = sp[mi][i];
      v += __shfl_xor(v, 1); v += __shfl_xor(v, 2);
      v += __shfl_xor(v, 4); v += __shfl_xor(v, 8);
      sp[mi][i] = v;
    }
  if (l16 == 0) {
#pragma unroll
    for (int mi = 0; mi < 4; ++mi)
#pragma unroll
      for (int i = 0; i < 4; ++i) ssc[wvv][mi * 16 + quad * 4 + i] = sp[mi][i];
  }
  __syncthreads();
  if (threadIdx.x < 64)
    scores[r0 + threadIdx.x] =
        ssc[0][threadIdx.x] + ssc[1][threadIdx.x] + ssc[2][threadIdx.x] + ssc[3][threadIdx.x];
}

// ---------------------------------------------------------------------------
// per-b softmax over t + r[b,h] = sum_t alpha[t] * Y[b,t,h]
// ---------------------------------------------------------------------------
__global__ __launch_bounds__(256) void softrv_kernel(const float* scores,
                                                     const unsigned short* op,
                                                     unsigned short* rbf) {
  const int b = blockIdx.x;
  const int tid = threadIdx.x, wvv = tid >> 6, lane = tid & 63;
  __shared__ float sal[128];
  __shared__ float red[8];
  float sv = -3.0e38f;
  if (tid < 128) sv = scores[tid * BB + b];
  float m = sv;
  m = fmaxf(m, __shfl_xor(m, 1));  m = fmaxf(m, __shfl_xor(m, 2));
  m = fmaxf(m, __shfl_xor(m, 4));  m = fmaxf(m, __shfl_xor(m, 8));
  m = fmaxf(m, __shfl_xor(m, 16)); m = fmaxf(m, __shfl_xor(m, 32));
  if (lane == 0) red[wvv] = m;
  __syncthreads();
  float M = fmaxf(fmaxf(red[0], red[1]), fmaxf(red[2], red[3]));
  float e = (tid < 128) ? __expf(sv - M) : 0.0f;
  float s = e;
  s += __shfl_xor(s, 1);  s += __shfl_xor(s, 2);  s += __shfl_xor(s, 4);
  s += __shfl_xor(s, 8);  s += __shfl_xor(s, 16); s += __shfl_xor(s, 32);
  if (lane == 0) red[4 + wvv] = s;
  __syncthreads();
  float S = red[4] + red[5] + red[6] + red[7];
  if (tid < 128) sal[tid] = e / S;
  __syncthreads();
  float a0 = 0, a1 = 0, a2 = 0, a3 = 0;
  const unsigned short* base = op + (size_t)b * HD + tid * 4;
  for (int t2 = 0; t2 < 128; ++t2) {
    float w = sal[t2];
    us4 v = *(const us4*)(base + (size_t)t2 * (BB * HD));
    a0 += w * b2f(v.x); a1 += w * b2f(v.y); a2 += w * b2f(v.z); a3 += w * b2f(v.w);
  }
  us4 o; o.x = f2b(a0); o.y = f2b(a1); o.z = f2b(a2); o.w = f2b(a3);
  *(us4*)(rbf + (size_t)b * HD + tid * 4) = o;
}

// ---------------------------------------------------------------------------
// h_star = tanh(r @ W_p + h_last @ W_x)
// ---------------------------------------------------------------------------
__global__ __launch_bounds__(256) void hstar_kernel(const unsigned short* rbf,
                                                    const unsigned short* hlast,
                                                    const unsigned short* WpT,
                                                    const unsigned short* WxT,
                                                    unsigned short* hstar) {
  const int wvv = threadIdx.x >> 6, lane = threadIdx.x & 63;
  const int quad = lane >> 4, l16 = lane & 15;
  const int m0 = (blockIdx.x >> 3) * 64, n0 = (blockIdx.x & 7) * 128 + wvv * 32;
  const f32x4 zf = {0.f, 0.f, 0.f, 0.f};
  f32x4 acc[4][2];
#pragma unroll
  for (int mi = 0; mi < 4; ++mi) { acc[mi][0] = zf; acc[mi][1] = zf; }
  for (int kk = 0; kk < 64; ++kk) {
    int k = (kk << 5) + (quad << 3);
    const unsigned short* Ap; const unsigned short* Bp; int kl;
    if (kk < 32) { Ap = rbf;   Bp = WpT; kl = k; }
    else         { Ap = hlast; Bp = WxT; kl = k - 1024; }
    short8 a[4], bb[2];
#pragma unroll
    for (int mi = 0; mi < 4; ++mi) a[mi] = ld8(Ap + (size_t)(m0 + mi * 16 + l16) * HD + kl);
#pragma unroll
    for (int nt = 0; nt < 2; ++nt) bb[nt] = ld8(Bp + (size_t)(n0 + nt * 16 + l16) * HD + kl);
#pragma unroll
    for (int mi = 0; mi < 4; ++mi)
#pragma unroll
      for (int nt = 0; nt < 2; ++nt) acc[mi][nt] = MFMA(a[mi], bb[nt], acc[mi][nt]);
  }
#pragma unroll
  for (int mi = 0; mi < 4; ++mi)
#pragma unroll
    for (int nt = 0; nt < 2; ++nt)
#pragma unroll
      for (int i = 0; i < 4; ++i)
        hstar[(size_t)(m0 + mi * 16 + quad * 4 + i) * HD + n0 + nt * 16 + l16] =
            f2b(tanh_f(acc[mi][nt][i]));
}

// ---------------------------------------------------------------------------
// logits = tanh(h_star @ out_w^T + out_b); out = log_softmax (dtype-matched)
// ---------------------------------------------------------------------------
__global__ __launch_bounds__(64) void out_kernel(const unsigned short* hstar,
                                                 DIn outw, DIn outb,
                                                 void* dout, const int* flag) {
  const int isf = *flag;
  const int b = blockIdx.x, lane = threadIdx.x;
  float l0 = 0, l1 = 0, l2 = 0;
  const short8* ph = (const short8*)(hstar + (size_t)b * HD + lane * 16);
  short8 h0 = ph[0], h1 = ph[1];
  for (int c = 0; c < 3; ++c) {
    short8 w0 = ld8i(outw, (size_t)c * HD + lane * 16, isf);
    short8 w1 = ld8i(outw, (size_t)c * HD + lane * 16 + 8, isf);
    float s = 0;
#pragma unroll
    for (int j = 0; j < 8; ++j)
      s += b2f((unsigned short)h0[j]) * b2f((unsigned short)w0[j]) +
           b2f((unsigned short)h1[j]) * b2f((unsigned short)w1[j]);
    s += __shfl_xor(s, 1);  s += __shfl_xor(s, 2);  s += __shfl_xor(s, 4);
    s += __shfl_xor(s, 8);  s += __shfl_xor(s, 16); s += __shfl_xor(s, 32);
    float v = tanh_f(s + ld1i(outb, c, isf));
    if (c == 0) l0 = v; else if (c == 1) l1 = v; else l2 = v;
  }
  float mx = fmaxf(l0, fmaxf(l1, l2));
  float lse = mx + logf(__expf(l0 - mx) + __expf(l1 - mx) + __expf(l2 - mx));
  if (lane < 3) {
    float v = ((lane == 0) ? l0 : (lane == 1) ? l1 : l2) - lse;
    if (isf) ((float*)dout)[b * 3 + lane] = v;
    else     ((unsigned short*)dout)[b * 3 + lane] = f2b(v);
  }
}

// ---------------------------------------------------------------------------
extern "C" void kernel_launch(void* const* d_in, const int* in_sizes, int n_in,
                              void* d_out, int out_size, void* d_ws, size_t ws_size,
                              hipStream_t stream) {
  DIn prem{(const unsigned short*)d_in[0],  (const float*)d_in[0]};
  DIn hyp {(const unsigned short*)d_in[1],  (const float*)d_in[1]};
  DIn pWih{(const unsigned short*)d_in[2],  (const float*)d_in[2]};
  DIn pWhh{(const unsigned short*)d_in[3],  (const float*)d_in[3]};
  DIn pbih{(const unsigned short*)d_in[4],  (const float*)d_in[4]};
  DIn pbhh{(const unsigned short*)d_in[5],  (const float*)d_in[5]};
  DIn hWih{(const unsigned short*)d_in[6],  (const float*)d_in[6]};
  DIn hWhh{(const unsigned short*)d_in[7],  (const float*)d_in[7]};
  DIn hbih{(const unsigned short*)d_in[8],  (const float*)d_in[8]};
  DIn hbhh{(const unsigned short*)d_in[9],  (const float*)d_in[9]};
  DIn Wy  {(const unsigned short*)d_in[10], (const float*)d_in[10]};
  DIn Whm {(const unsigned short*)d_in[11], (const float*)d_in[11]};
  DIn Wal {(const unsigned short*)d_in[12], (const float*)d_in[12]};
  DIn Wx  {(const unsigned short*)d_in[13], (const float*)d_in[13]};
  DIn Wp  {(const unsigned short*)d_in[14], (const float*)d_in[14]};
  DIn outw{(const unsigned short*)d_in[15], (const float*)d_in[15]};
  DIn outb{(const unsigned short*)d_in[16], (const float*)d_in[16]};

  // Workspace: 62 MB total (transposes overlaid in tb0/tb1)
  char* ws = (char*)d_ws;
  int*            bar   = (int*)ws;                          // barrier flags + dtype flag
  unsigned short* hbuf  = (unsigned short*)(ws + 4096);      // 512 KB
  float*          WhRes = (float*)(ws + 528384);             // 512 KB
  float*          scr   = (float*)(ws + 1052672);            // 64 KB
  unsigned short* rbf   = (unsigned short*)(ws + 1118208);   // 256 KB
  unsigned short* hstar = (unsigned short*)(ws + 1380352);   // 256 KB
  unsigned short* tb0   = (unsigned short*)(ws + 2097152);   // 2 MB
  unsigned short* tb1   = (unsigned short*)(ws + 4194304);   // 2 MB
  unsigned short* op    = (unsigned short*)(ws + 6291456);   // 32 MB -> ends 38 MB
  unsigned short* cWihP = (unsigned short*)(ws + 39845888);  // 6 MB bf16 weights
  unsigned short* cWhhP = (unsigned short*)(ws + 46137344);  // 6 MB
  unsigned short* cWihH = (unsigned short*)(ws + 52428800);  // 6 MB
  unsigned short* cWhhH = (unsigned short*)(ws + 58720256);  // 6 MB -> ends 62 MB

  hipMemsetAsync(d_ws, 0, 4096, stream);
  hipLaunchKernelGGL(probe_kernel, dim3(1), dim3(64), 0, stream,
                     (const unsigned char*)d_in[0], bar + 992);

  // one-time bf16 weight conversion (3072*1024 each; grid 1536*256*8 exact)
  hipLaunchKernelGGL(conv_kernel, dim3(1536), dim3(256), 0, stream, pWih, cWihP, bar + 992);
  hipLaunchKernelGGL(conv_kernel, dim3(1536), dim3(256), 0, stream, pWhh, cWhhP, bar + 992);
  hipLaunchKernelGGL(conv_kernel, dim3(1536), dim3(256), 0, stream, hWih, cWihH, bar + 992);
  hipLaunchKernelGGL(conv_kernel, dim3(1536), dim3(256), 0, stream, hWhh, cWhhH, bar + 992);

  ScanParams sp{prem, hyp, pbih, pbhh, hbih, hbhh,
                cWihP, cWhhP, cWihH, cWhhH, hbuf, op, bar};
  hipLaunchKernelGGL(scan_kernel, dim3(256), dim3(256), 0, stream, sp);

  hipLaunchKernelGGL(transpose_kernel, dim3(256), dim3(256), 0, stream, Whm, tb0, bar + 992);
  hipLaunchKernelGGL(wh_kernel, dim3(16), dim3(256), 0, stream, hbuf, tb0, WhRes);

  hipLaunchKernelGGL(transpose_kernel, dim3(256), dim3(256), 0, stream, Wy, tb0, bar + 992);
  hipLaunchKernelGGL(score_kernel, dim3(256), dim3(256), 0, stream, op, tb0, WhRes,
                     Wal, scr, bar + 992);
  hipLaunchKernelGGL(softrv_kernel, dim3(128), dim3(256), 0, stream, scr, op, rbf);

  hipLaunchKernelGGL(transpose_kernel, dim3(256), dim3(256), 0, stream, Wp, tb0, bar + 992);
  hipLaunchKernelGGL(transpose_kernel, dim3(256), dim3(256), 0, stream, Wx, tb1, bar + 992);
  hipLaunchKernelGGL(hstar_kernel, dim3(16), dim3(256), 0, stream, rbf, hbuf, tb0, tb1, hstar);

  hipLaunchKernelGGL(out_kernel, dim3(128), dim3(64), 0, stream, hstar, outw, outb,
                     d_out, bar + 992);
}

// Round 3
// 5636.891 us; speedup vs baseline: 3.9302x; 1.5254x over previous
//
#include <hip/hip_runtime.h>

#define HD 1024
#define BB 128
#define TT 128

typedef short short8 __attribute__((ext_vector_type(8)));
typedef float f32x4 __attribute__((ext_vector_type(4)));
typedef unsigned short us4 __attribute__((ext_vector_type(4)));

#define MFMA(a, b, c) __builtin_amdgcn_mfma_f32_16x16x32_bf16((a), (b), (c), 0, 0, 0)

__device__ __forceinline__ float b2f(unsigned short u) {
  union { unsigned int i; float f; } v; v.i = ((unsigned int)u) << 16; return v.f;
}
__device__ __forceinline__ unsigned short f2b(float f) {
  union { float f; unsigned int i; } v; v.f = f;
  unsigned int i = v.i;
  return (unsigned short)((i + 0x7FFFu + ((i >> 16) & 1u)) >> 16);
}
__device__ __forceinline__ short8 ld8(const unsigned short* p) {
  return *reinterpret_cast<const short8*>(p);
}

// Dual-dtype input view: same base pointer, interpreted per runtime flag.
struct DIn { const unsigned short* h; const float* f; };

__device__ __forceinline__ short8 ld8i(const DIn in, size_t idx, int isf) {
  if (isf) {
    const float4* p = (const float4*)(in.f + idx);
    float4 a = p[0], b = p[1];
    short8 r;
    r[0] = (short)f2b(a.x); r[1] = (short)f2b(a.y);
    r[2] = (short)f2b(a.z); r[3] = (short)f2b(a.w);
    r[4] = (short)f2b(b.x); r[5] = (short)f2b(b.y);
    r[6] = (short)f2b(b.z); r[7] = (short)f2b(b.w);
    return r;
  }
  return ld8(in.h + idx);
}
__device__ __forceinline__ float ld1i(const DIn in, size_t idx, int isf) {
  return isf ? in.f[idx] : b2f(in.h[idx]);
}
// Device-coherent 16B load (agent-scope relaxed -> sc1, bypasses L1/per-XCD L2)
__device__ __forceinline__ short8 ld8_coh(const unsigned long long* q) {
  union { unsigned long long u[2]; short8 s; } v;
  v.u[0] = __hip_atomic_load((unsigned long long*)q,     __ATOMIC_RELAXED, __HIP_MEMORY_SCOPE_AGENT);
  v.u[1] = __hip_atomic_load((unsigned long long*)q + 1, __ATOMIC_RELAXED, __HIP_MEMORY_SCOPE_AGENT);
  return v.s;
}
__device__ __forceinline__ float sigm(float x) {
  x = fminf(fmaxf(x, -30.f), 30.f);
  return 1.0f / (1.0f + __expf(-x));
}
__device__ __forceinline__ float tanh_f(float x) {
  x = fminf(fmaxf(x, -15.f), 15.f);
  float e = __expf(2.0f * x);
  return (e - 1.0f) / (e + 1.0f);
}

// ---------------------------------------------------------------------------
// Dtype probe: byte at offset 4i+1 is exp-structured iff data is bf16.
// flag: 0 = bf16, 1 = fp32.  (flag lives at bar[992])
// ---------------------------------------------------------------------------
__global__ __launch_bounds__(64) void probe_kernel(const unsigned char* p, int* flag) {
  int t = threadIdx.x;
  unsigned char b = p[t * 4 + 1] & 0x7F;
  int s = (b >= 0x34 && b <= 0x41) ? 1 : 0;
  s += __shfl_xor(s, 1);  s += __shfl_xor(s, 2);  s += __shfl_xor(s, 4);
  s += __shfl_xor(s, 8);  s += __shfl_xor(s, 16); s += __shfl_xor(s, 32);
  if (t == 0) *flag = (s > 32) ? 0 : 1;
}

// ---------------------------------------------------------------------------
// One-time weight conversion -> bf16 (copy if already bf16).
// ---------------------------------------------------------------------------
__global__ __launch_bounds__(256) void conv_kernel(DIn in, unsigned short* out,
                                                   const int* flag) {
  const int isf = *flag;
  size_t i = ((size_t)blockIdx.x * 256 + threadIdx.x) * 8;
  *(short8*)(out + i) = ld8i(in, i, isf);
}

// ---------------------------------------------------------------------------
// Persistent GRU scan. Changes vs previous round:
//  - per-bc barrier: the 4 batch-row groups (64 WGs each) sync independently
//    (batch rows are recurrence-independent). One store->poll hop: WG stores
//    its own flag dword; wave0's 64 lanes ballot-poll the group's 64 flags.
//  - all 4 waves K-split gh 4-way (8 iters each) with BURST h-preload:
//    all 16 agent-scope h loads issued up front into registers, collapsing
//    the serial MALL chain to ~1 round trip.
//  - gx prefetch also 4-way split, overlapped with the barrier window.
// Barrier layout in bar[]: group bc flags at bar[256+64*bc .. +63];
//   bar[992] dtype flag.
// ---------------------------------------------------------------------------
struct ScanParams {
  DIn prem, hyp;
  DIn pbih, pbhh, hbih, hbhh;
  const unsigned short *cWihP, *cWhhP, *cWihH, *cWhhH;  // bf16 weights
  unsigned short *hbuf;   // [2][128][1024] bf16 (agent-coherent accesses)
  unsigned short *op;     // [128][128][1024] bf16 (premise outputs, t-major)
  int *bar;
};

__global__ __launch_bounds__(256) void scan_kernel(ScanParams P) {
  const int tid = threadIdx.x;
  const int wv = tid >> 6;
  const int lane = tid & 63;
  const int quad = lane >> 4, l16 = lane & 15;
  const int bid = blockIdx.x;
  const int xcd = bid & 7;
  const int y = bid >> 3;
  const int jg = (xcd << 3) | (y & 7);
  const int bc = y >> 3;
  const int row0 = bc << 5;
  const int col0 = jg << 4;
  const int mem = bid & 63;          // member index within bc group
  const int isf = P.bar[992];

  __shared__ float s_gh[4][32][52];
  __shared__ float s_gx[4][32][52];
  __shared__ float s_h[32][16];

  const int er = tid >> 2;            // valid for tid < 128
  const int ec0 = (tid & 3) << 2;

  if (tid < 128)
    for (int q = 0; q < 4; ++q) s_h[er][ec0 + q] = 0.0f;

  float bir[4], biz[4], bin_[4], bhr[4], bhz[4], bhn[4];
  f32x4 gxa[2][3];
  const f32x4 zf = {0.f, 0.f, 0.f, 0.f};

  int* gflag = P.bar + 256 + (bc << 6);
  const int kk0 = wv << 3;            // this wave's K-slice (8 iters)

  // prologue: gx(0), all 4 waves K-split
  {
#pragma unroll
    for (int mi = 0; mi < 2; ++mi)
#pragma unroll
      for (int gi = 0; gi < 3; ++gi) gxa[mi][gi] = zf;
    const size_t x0 = (size_t)(row0 + l16) * TT * HD;
    const size_t x1 = (size_t)(row0 + 16 + l16) * TT * HD;
#pragma unroll 2
    for (int kk = kk0; kk < kk0 + 8; ++kk) {
      int k = (kk << 5) + (quad << 3);
      short8 a0 = ld8i(P.prem, x0 + k, isf);
      short8 a1 = ld8i(P.prem, x1 + k, isf);
#pragma unroll
      for (int gi = 0; gi < 3; ++gi) {
        short8 b = ld8(P.cWihP + (size_t)((gi << 10) + col0 + l16) * HD + k);
        gxa[0][gi] = MFMA(a0, b, gxa[0][gi]);
        gxa[1][gi] = MFMA(a1, b, gxa[1][gi]);
      }
    }
  }

  for (int t = 0; t < 256; ++t) {
    // write gx partials (from prefetch regs)
#pragma unroll
    for (int mi = 0; mi < 2; ++mi)
#pragma unroll
      for (int gi = 0; gi < 3; ++gi)
#pragma unroll
        for (int i = 0; i < 4; ++i)
          s_gx[wv][(mi << 4) + (quad << 2) + i][(gi << 4) + l16] = gxa[mi][gi][i];

    // gh(t), 4-way K-split, burst h-preload
    {
      f32x4 gha[2][3];
#pragma unroll
      for (int mi = 0; mi < 2; ++mi)
#pragma unroll
        for (int gi = 0; gi < 3; ++gi) gha[mi][gi] = zf;
      if (t > 0) {
        const unsigned long long* hq =
            (const unsigned long long*)P.hbuf + (((size_t)(t & 1) * (BB * HD)) >> 2);
        const unsigned short* W = (t < 128) ? P.cWhhP : P.cWhhH;
        const unsigned long long* q0 = hq + (((size_t)(row0 + l16) * HD) >> 2);
        const unsigned long long* q1 = hq + (((size_t)(row0 + 16 + l16) * HD) >> 2);
        short8 ha[8], hb[8];
#pragma unroll
        for (int u = 0; u < 8; ++u) {
          int k = ((kk0 + u) << 5) + (quad << 3);
          ha[u] = ld8_coh(q0 + (k >> 2));
          hb[u] = ld8_coh(q1 + (k >> 2));
        }
#pragma unroll
        for (int u = 0; u < 8; ++u) {
          int k = ((kk0 + u) << 5) + (quad << 3);
#pragma unroll
          for (int gi = 0; gi < 3; ++gi) {
            short8 b = ld8(W + (size_t)((gi << 10) + col0 + l16) * HD + k);
            gha[0][gi] = MFMA(ha[u], b, gha[0][gi]);
            gha[1][gi] = MFMA(hb[u], b, gha[1][gi]);
          }
        }
      }
#pragma unroll
      for (int mi = 0; mi < 2; ++mi)
#pragma unroll
        for (int gi = 0; gi < 3; ++gi)
#pragma unroll
          for (int i = 0; i < 4; ++i)
            s_gh[wv][(mi << 4) + (quad << 2) + i][(gi << 4) + l16] = gha[mi][gi][i];
    }
    __syncthreads();

    if ((t == 0 || t == 128) && tid < 128) {
      const DIn bih = (t < 128) ? P.pbih : P.hbih;
      const DIn bhh = (t < 128) ? P.pbhh : P.hbhh;
#pragma unroll
      for (int q = 0; q < 4; ++q) {
        int g = col0 + ec0 + q;
        bir[q] = ld1i(bih, g, isf);  biz[q] = ld1i(bih, 1024 + g, isf);
        bin_[q] = ld1i(bih, 2048 + g, isf);
        bhr[q] = ld1i(bhh, g, isf);  bhz[q] = ld1i(bhh, 1024 + g, isf);
        bhn[q] = ld1i(bhh, 2048 + g, isf);
      }
    }

    // GRU cell (torch equations), fp32 — threads 0..127, 4-way partial sums
    if (tid < 128) {
      unsigned short hout[4];
#pragma unroll
      for (int q = 0; q < 4; ++q) {
        int c = ec0 + q;
        float gxr = s_gx[0][er][c]      + s_gx[1][er][c]
                  + s_gx[2][er][c]      + s_gx[3][er][c];
        float gxz = s_gx[0][er][16 + c] + s_gx[1][er][16 + c]
                  + s_gx[2][er][16 + c] + s_gx[3][er][16 + c];
        float gxn = s_gx[0][er][32 + c] + s_gx[1][er][32 + c]
                  + s_gx[2][er][32 + c] + s_gx[3][er][32 + c];
        float ghr = s_gh[0][er][c]      + s_gh[1][er][c]
                  + s_gh[2][er][c]      + s_gh[3][er][c];
        float ghz = s_gh[0][er][16 + c] + s_gh[1][er][16 + c]
                  + s_gh[2][er][16 + c] + s_gh[3][er][16 + c];
        float ghn = s_gh[0][er][32 + c] + s_gh[1][er][32 + c]
                  + s_gh[2][er][32 + c] + s_gh[3][er][32 + c];
        float r = sigm(gxr + bir[q] + ghr + bhr[q]);
        float z = sigm(gxz + biz[q] + ghz + bhz[q]);
        float n = tanh_f(gxn + bin_[q] + r * (ghn + bhn[q]));
        float h = (1.0f - z) * n + z * s_h[er][c];
        s_h[er][c] = h;
        hout[q] = f2b(h);
      }
      union { us4 v; unsigned long long q; } pv;
      pv.v.x = hout[0]; pv.v.y = hout[1]; pv.v.z = hout[2]; pv.v.w = hout[3];
      int grow = row0 + er, gcol = col0 + ec0;
      size_t idx = ((size_t)((t + 1) & 1) * (BB * HD) + (size_t)grow * HD + gcol) >> 2;
      __hip_atomic_store((unsigned long long*)P.hbuf + idx, pv.q,
                         __ATOMIC_RELAXED, __HIP_MEMORY_SCOPE_AGENT);
      if (t < 128)
        *(us4*)(P.op + (size_t)t * (BB * HD) + (size_t)grow * HD + gcol) = pv.v;
    }
    __syncthreads();   // drains vmcnt(0): h-stores visible before arrival flag

    if (t == 255) break;

    // arrival: each WG stores its own flag dword in its bc group's region
    if (tid == 0)
      __hip_atomic_store(gflag + mem, t + 1, __ATOMIC_RELAXED,
                         __HIP_MEMORY_SCOPE_AGENT);

    // all waves: prefetch gx(t+1) during the barrier window (4-way K-split)
    {
      int tn = t + 1;
      const DIn X = (tn < 128) ? P.prem : P.hyp;
      const unsigned short* Wi = (tn < 128) ? P.cWihP : P.cWihH;
      int tl = tn & 127;
#pragma unroll
      for (int mi = 0; mi < 2; ++mi)
#pragma unroll
        for (int gi = 0; gi < 3; ++gi) gxa[mi][gi] = zf;
      const size_t x0 = ((size_t)(row0 + l16) * TT + tl) * HD;
      const size_t x1 = ((size_t)(row0 + 16 + l16) * TT + tl) * HD;
#pragma unroll 2
      for (int kk = kk0; kk < kk0 + 8; ++kk) {
        int k = (kk << 5) + (quad << 3);
        short8 a0 = ld8i(X, x0 + k, isf);
        short8 a1 = ld8i(X, x1 + k, isf);
#pragma unroll
        for (int gi = 0; gi < 3; ++gi) {
          short8 b = ld8(Wi + (size_t)((gi << 10) + col0 + l16) * HD + k);
          gxa[0][gi] = MFMA(a0, b, gxa[0][gi]);
          gxa[1][gi] = MFMA(a1, b, gxa[1][gi]);
        }
      }
    }

    // release: wave0's 64 lanes ballot-poll the group's 64 flags (1 hop)
    if (wv == 0) {
      for (;;) {
        int v = __hip_atomic_load(gflag + lane, __ATOMIC_RELAXED,
                                  __HIP_MEMORY_SCOPE_AGENT);
        if (__ballot(v >= t + 1) == ~0ull) break;
        __builtin_amdgcn_s_sleep(2);
      }
    }
    __syncthreads();
  }
}

// ---------------------------------------------------------------------------
// 1024x1024 transpose, dual-dtype input -> bf16 out
// ---------------------------------------------------------------------------
__global__ __launch_bounds__(256) void transpose_kernel(DIn in, unsigned short* out,
                                                        const int* flag) {
  __shared__ unsigned short tile[64][65];
  const int isf = *flag;
  const int b = blockIdx.x;
  const int d0 = (b & 15) << 6, h0 = (b >> 4) << 6;
  const int c = threadIdx.x & 63, rg = threadIdx.x >> 6;
#pragma unroll
  for (int i = 0; i < 16; ++i) {
    int r = (rg << 4) + i;
    size_t idx = (size_t)(h0 + r) * HD + d0 + c;
    tile[r][c] = isf ? f2b(in.f[idx]) : in.h[idx];
  }
  __syncthreads();
#pragma unroll
  for (int i = 0; i < 16; ++i) {
    int r = (rg << 4) + i;
    out[(size_t)(d0 + r) * HD + h0 + c] = tile[c][r];
  }
}

// ---------------------------------------------------------------------------
// Wh = h_last @ W_h -> f32 [128][1024]  (Bt = transposed weight, bf16)
// ---------------------------------------------------------------------------
__global__ __launch_bounds__(256) void wh_kernel(const unsigned short* A,
                                                 const unsigned short* Bt, float* out) {
  const int wvv = threadIdx.x >> 6, lane = threadIdx.x & 63;
  const int quad = lane >> 4, l16 = lane & 15;
  const int m0 = (blockIdx.x >> 3) * 64, n0 = (blockIdx.x & 7) * 128 + wvv * 32;
  const f32x4 zf = {0.f, 0.f, 0.f, 0.f};
  f32x4 acc[4][2];
#pragma unroll
  for (int mi = 0; mi < 4; ++mi) { acc[mi][0] = zf; acc[mi][1] = zf; }
  for (int kk = 0; kk < 32; ++kk) {
    int k = (kk << 5) + (quad << 3);
    short8 a[4], bb[2];
#pragma unroll
    for (int mi = 0; mi < 4; ++mi) a[mi] = ld8(A + (size_t)(m0 + mi * 16 + l16) * HD + k);
#pragma unroll
    for (int nt = 0; nt < 2; ++nt) bb[nt] = ld8(Bt + (size_t)(n0 + nt * 16 + l16) * HD + k);
#pragma unroll
    for (int mi = 0; mi < 4; ++mi)
#pragma unroll
      for (int nt = 0; nt < 2; ++nt) acc[mi][nt] = MFMA(a[mi], bb[nt], acc[mi][nt]);
  }
#pragma unroll
  for (int mi = 0; mi < 4; ++mi)
#pragma unroll
    for (int nt = 0; nt < 2; ++nt)
#pragma unroll
      for (int i = 0; i < 4; ++i)
        out[(size_t)(m0 + mi * 16 + quad * 4 + i) * HD + n0 + nt * 16 + l16] = acc[mi][nt][i];
}

// ---------------------------------------------------------------------------
// scores[r=(t,b)] = sum_d tanh(Y@W_y[r,d] + Wh[b,d]) * Walpha[d]
// ---------------------------------------------------------------------------
__global__ __launch_bounds__(256) void score_kernel(const unsigned short* op,
                                                    const unsigned short* WyT,
                                                    const float* Wh,
                                                    DIn Walpha,
                                                    float* scores,
                                                    const int* flag) {
  const int isf = *flag;
  const int wvv = threadIdx.x >> 6, lane = threadIdx.x & 63;
  const int quad = lane >> 4, l16 = lane & 15;
  const int r0 = blockIdx.x * 64;
  __shared__ float ssc[4][64];
  float sp[4][4];
#pragma unroll
  for (int mi = 0; mi < 4; ++mi)
#pragma unroll
    for (int i = 0; i < 4; ++i) sp[mi][i] = 0.f;
  const f32x4 zf = {0.f, 0.f, 0.f, 0.f};

  for (int dc = 0; dc < 8; ++dc) {
    const int n0 = dc * 128 + wvv * 32;
    f32x4 acc[4][2];
#pragma unroll
    for (int mi = 0; mi < 4; ++mi) { acc[mi][0] = zf; acc[mi][1] = zf; }
    for (int kk = 0; kk < 32; ++kk) {
      int k = (kk << 5) + (quad << 3);
      short8 a[4], bb[2];
#pragma unroll
      for (int mi = 0; mi < 4; ++mi) a[mi] = ld8(op + (size_t)(r0 + mi * 16 + l16) * HD + k);
#pragma unroll
      for (int nt = 0; nt < 2; ++nt) bb[nt] = ld8(WyT + (size_t)(n0 + nt * 16 + l16) * HD + k);
#pragma unroll
      for (int mi = 0; mi < 4; ++mi)
#pragma unroll
        for (int nt = 0; nt < 2; ++nt) acc[mi][nt] = MFMA(a[mi], bb[nt], acc[mi][nt]);
    }
    float wa[2];
#pragma unroll
    for (int nt = 0; nt < 2; ++nt) wa[nt] = ld1i(Walpha, n0 + nt * 16 + l16, isf);
#pragma unroll
    for (int mi = 0; mi < 4; ++mi)
#pragma unroll
      for (int nt = 0; nt < 2; ++nt)
#pragma unroll
        for (int i = 0; i < 4; ++i) {
          int r = r0 + mi * 16 + quad * 4 + i;
          int bb2 = r & 127;
          int d = n0 + nt * 16 + l16;
          float v = tanh_f(acc[mi][nt][i] + Wh[(size_t)bb2 * HD + d]);
          sp[mi][i] += v * wa[nt];
        }
  }
#pragma unroll
  for (int mi = 0; mi < 4; ++mi)
#pragma unroll
    for (int i = 0; i < 4; ++i) {
      float v = sp[mi][i];
      v += __shfl_xor(v, 1); v += __shfl_xor(v, 2);
      v += __shfl_xor(v, 4); v += __shfl_xor(v, 8);
      sp[mi][i] = v;
    }
  if (l16 == 0) {
#pragma unroll
    for (int mi = 0; mi < 4; ++mi)
#pragma unroll
      for (int i = 0; i < 4; ++i) ssc[wvv][mi * 16 + quad * 4 + i] = sp[mi][i];
  }
  __syncthreads();
  if (threadIdx.x < 64)
    scores[r0 + threadIdx.x] =
        ssc[0][threadIdx.x] + ssc[1][threadIdx.x] + ssc[2][threadIdx.x] + ssc[3][threadIdx.x];
}

// ---------------------------------------------------------------------------
// per-b softmax over t + r[b,h] = sum_t alpha[t] * Y[b,t,h]
// ---------------------------------------------------------------------------
__global__ __launch_bounds__(256) void softrv_kernel(const float* scores,
                                                     const unsigned short* op,
                                                     unsigned short* rbf) {
  const int b = blockIdx.x;
  const int tid = threadIdx.x, wvv = tid >> 6, lane = tid & 63;
  __shared__ float sal[128];
  __shared__ float red[8];
  float sv = -3.0e38f;
  if (tid < 128) sv = scores[tid * BB + b];
  float m = sv;
  m = fmaxf(m, __shfl_xor(m, 1));  m = fmaxf(m, __shfl_xor(m, 2));
  m = fmaxf(m, __shfl_xor(m, 4));  m = fmaxf(m, __shfl_xor(m, 8));
  m = fmaxf(m, __shfl_xor(m, 16)); m = fmaxf(m, __shfl_xor(m, 32));
  if (lane == 0) red[wvv] = m;
  __syncthreads();
  float M = fmaxf(fmaxf(red[0], red[1]), fmaxf(red[2], red[3]));
  float e = (tid < 128) ? __expf(sv - M) : 0.0f;
  float s = e;
  s += __shfl_xor(s, 1);  s += __shfl_xor(s, 2);  s += __shfl_xor(s, 4);
  s += __shfl_xor(s, 8);  s += __shfl_xor(s, 16); s += __shfl_xor(s, 32);
  if (lane == 0) red[4 + wvv] = s;
  __syncthreads();
  float S = red[4] + red[5] + red[6] + red[7];
  if (tid < 128) sal[tid] = e / S;
  __syncthreads();
  float a0 = 0, a1 = 0, a2 = 0, a3 = 0;
  const unsigned short* base = op + (size_t)b * HD + tid * 4;
  for (int t2 = 0; t2 < 128; ++t2) {
    float w = sal[t2];
    us4 v = *(const us4*)(base + (size_t)t2 * (BB * HD));
    a0 += w * b2f(v.x); a1 += w * b2f(v.y); a2 += w * b2f(v.z); a3 += w * b2f(v.w);
  }
  us4 o; o.x = f2b(a0); o.y = f2b(a1); o.z = f2b(a2); o.w = f2b(a3);
  *(us4*)(rbf + (size_t)b * HD + tid * 4) = o;
}

// ---------------------------------------------------------------------------
// h_star = tanh(r @ W_p + h_last @ W_x)
// ---------------------------------------------------------------------------
__global__ __launch_bounds__(256) void hstar_kernel(const unsigned short* rbf,
                                                    const unsigned short* hlast,
                                                    const unsigned short* WpT,
                                                    const unsigned short* WxT,
                                                    unsigned short* hstar) {
  const int wvv = threadIdx.x >> 6, lane = threadIdx.x & 63;
  const int quad = lane >> 4, l16 = lane & 15;
  const int m0 = (blockIdx.x >> 3) * 64, n0 = (blockIdx.x & 7) * 128 + wvv * 32;
  const f32x4 zf = {0.f, 0.f, 0.f, 0.f};
  f32x4 acc[4][2];
#pragma unroll
  for (int mi = 0; mi < 4; ++mi) { acc[mi][0] = zf; acc[mi][1] = zf; }
  for (int kk = 0; kk < 64; ++kk) {
    int k = (kk << 5) + (quad << 3);
    const unsigned short* Ap; const unsigned short* Bp; int kl;
    if (kk < 32) { Ap = rbf;   Bp = WpT; kl = k; }
    else         { Ap = hlast; Bp = WxT; kl = k - 1024; }
    short8 a[4], bb[2];
#pragma unroll
    for (int mi = 0; mi < 4; ++mi) a[mi] = ld8(Ap + (size_t)(m0 + mi * 16 + l16) * HD + kl);
#pragma unroll
    for (int nt = 0; nt < 2; ++nt) bb[nt] = ld8(Bp + (size_t)(n0 + nt * 16 + l16) * HD + kl);
#pragma unroll
    for (int mi = 0; mi < 4; ++mi)
#pragma unroll
      for (int nt = 0; nt < 2; ++nt) acc[mi][nt] = MFMA(a[mi], bb[nt], acc[mi][nt]);
  }
#pragma unroll
  for (int mi = 0; mi < 4; ++mi)
#pragma unroll
    for (int nt = 0; nt < 2; ++nt)
#pragma unroll
      for (int i = 0; i < 4; ++i)
        hstar[(size_t)(m0 + mi * 16 + quad * 4 + i) * HD + n0 + nt * 16 + l16] =
            f2b(tanh_f(acc[mi][nt][i]));
}

// ---------------------------------------------------------------------------
// logits = tanh(h_star @ out_w^T + out_b); out = log_softmax (dtype-matched)
// ---------------------------------------------------------------------------
__global__ __launch_bounds__(64) void out_kernel(const unsigned short* hstar,
                                                 DIn outw, DIn outb,
                                                 void* dout, const int* flag) {
  const int isf = *flag;
  const int b = blockIdx.x, lane = threadIdx.x;
  float l0 = 0, l1 = 0, l2 = 0;
  const short8* ph = (const short8*)(hstar + (size_t)b * HD + lane * 16);
  short8 h0 = ph[0], h1 = ph[1];
  for (int c = 0; c < 3; ++c) {
    short8 w0 = ld8i(outw, (size_t)c * HD + lane * 16, isf);
    short8 w1 = ld8i(outw, (size_t)c * HD + lane * 16 + 8, isf);
    float s = 0;
#pragma unroll
    for (int j = 0; j < 8; ++j)
      s += b2f((unsigned short)h0[j]) * b2f((unsigned short)w0[j]) +
           b2f((unsigned short)h1[j]) * b2f((unsigned short)w1[j]);
    s += __shfl_xor(s, 1);  s += __shfl_xor(s, 2);  s += __shfl_xor(s, 4);
    s += __shfl_xor(s, 8);  s += __shfl_xor(s, 16); s += __shfl_xor(s, 32);
    float v = tanh_f(s + ld1i(outb, c, isf));
    if (c == 0) l0 = v; else if (c == 1) l1 = v; else l2 = v;
  }
  float mx = fmaxf(l0, fmaxf(l1, l2));
  float lse = mx + logf(__expf(l0 - mx) + __expf(l1 - mx) + __expf(l2 - mx));
  if (lane < 3) {
    float v = ((lane == 0) ? l0 : (lane == 1) ? l1 : l2) - lse;
    if (isf) ((float*)dout)[b * 3 + lane] = v;
    else     ((unsigned short*)dout)[b * 3 + lane] = f2b(v);
  }
}

// ---------------------------------------------------------------------------
extern "C" void kernel_launch(void* const* d_in, const int* in_sizes, int n_in,
                              void* d_out, int out_size, void* d_ws, size_t ws_size,
                              hipStream_t stream) {
  DIn prem{(const unsigned short*)d_in[0],  (const float*)d_in[0]};
  DIn hyp {(const unsigned short*)d_in[1],  (const float*)d_in[1]};
  DIn pWih{(const unsigned short*)d_in[2],  (const float*)d_in[2]};
  DIn pWhh{(const unsigned short*)d_in[3],  (const float*)d_in[3]};
  DIn pbih{(const unsigned short*)d_in[4],  (const float*)d_in[4]};
  DIn pbhh{(const unsigned short*)d_in[5],  (const float*)d_in[5]};
  DIn hWih{(const unsigned short*)d_in[6],  (const float*)d_in[6]};
  DIn hWhh{(const unsigned short*)d_in[7],  (const float*)d_in[7]};
  DIn hbih{(const unsigned short*)d_in[8],  (const float*)d_in[8]};
  DIn hbhh{(const unsigned short*)d_in[9],  (const float*)d_in[9]};
  DIn Wy  {(const unsigned short*)d_in[10], (const float*)d_in[10]};
  DIn Whm {(const unsigned short*)d_in[11], (const float*)d_in[11]};
  DIn Wal {(const unsigned short*)d_in[12], (const float*)d_in[12]};
  DIn Wx  {(const unsigned short*)d_in[13], (const float*)d_in[13]};
  DIn Wp  {(const unsigned short*)d_in[14], (const float*)d_in[14]};
  DIn outw{(const unsigned short*)d_in[15], (const float*)d_in[15]};
  DIn outb{(const unsigned short*)d_in[16], (const float*)d_in[16]};

  // Workspace: 62 MB total (transposes overlaid in tb0/tb1)
  char* ws = (char*)d_ws;
  int*            bar   = (int*)ws;                          // barrier flags + dtype flag
  unsigned short* hbuf  = (unsigned short*)(ws + 4096);      // 512 KB
  float*          WhRes = (float*)(ws + 528384);             // 512 KB
  float*          scr   = (float*)(ws + 1052672);            // 64 KB
  unsigned short* rbf   = (unsigned short*)(ws + 1118208);   // 256 KB
  unsigned short* hstar = (unsigned short*)(ws + 1380352);   // 256 KB
  unsigned short* tb0   = (unsigned short*)(ws + 2097152);   // 2 MB
  unsigned short* tb1   = (unsigned short*)(ws + 4194304);   // 2 MB
  unsigned short* op    = (unsigned short*)(ws + 6291456);   // 32 MB -> ends 38 MB
  unsigned short* cWihP = (unsigned short*)(ws + 39845888);  // 6 MB bf16 weights
  unsigned short* cWhhP = (unsigned short*)(ws + 46137344);  // 6 MB
  unsigned short* cWihH = (unsigned short*)(ws + 52428800);  // 6 MB
  unsigned short* cWhhH = (unsigned short*)(ws + 58720256);  // 6 MB -> ends 62 MB

  hipMemsetAsync(d_ws, 0, 4096, stream);
  hipLaunchKernelGGL(probe_kernel, dim3(1), dim3(64), 0, stream,
                     (const unsigned char*)d_in[0], bar + 992);

  // one-time bf16 weight conversion (3072*1024 each; grid 1536*256*8 exact)
  hipLaunchKernelGGL(conv_kernel, dim3(1536), dim3(256), 0, stream, pWih, cWihP, bar + 992);
  hipLaunchKernelGGL(conv_kernel, dim3(1536), dim3(256), 0, stream, pWhh, cWhhP, bar + 992);
  hipLaunchKernelGGL(conv_kernel, dim3(1536), dim3(256), 0, stream, hWih, cWihH, bar + 992);
  hipLaunchKernelGGL(conv_kernel, dim3(1536), dim3(256), 0, stream, hWhh, cWhhH, bar + 992);

  ScanParams sp{prem, hyp, pbih, pbhh, hbih, hbhh,
                cWihP, cWhhP, cWihH, cWhhH, hbuf, op, bar};
  hipLaunchKernelGGL(scan_kernel, dim3(256), dim3(256), 0, stream, sp);

  hipLaunchKernelGGL(transpose_kernel, dim3(256), dim3(256), 0, stream, Whm, tb0, bar + 992);
  hipLaunchKernelGGL(wh_kernel, dim3(16), dim3(256), 0, stream, hbuf, tb0, WhRes);

  hipLaunchKernelGGL(transpose_kernel, dim3(256), dim3(256), 0, stream, Wy, tb0, bar + 992);
  hipLaunchKernelGGL(score_kernel, dim3(256), dim3(256), 0, stream, op, tb0, WhRes,
                     Wal, scr, bar + 992);
  hipLaunchKernelGGL(softrv_kernel, dim3(128), dim3(256), 0, stream, scr, op, rbf);

  hipLaunchKernelGGL(transpose_kernel, dim3(256), dim3(256), 0, stream, Wp, tb0, bar + 992);
  hipLaunchKernelGGL(transpose_kernel, dim3(256), dim3(256), 0, stream, Wx, tb1, bar + 992);
  hipLaunchKernelGGL(hstar_kernel, dim3(16), dim3(256), 0, stream, rbf, hbuf, tb0, tb1, hstar);

  hipLaunchKernelGGL(out_kernel, dim3(128), dim3(64), 0, stream, hstar, outw, outb,
                     d_out, bar + 992);
}